// Round 3
// baseline (268.080 us; speedup 1.0000x reference)
//
#include <hip/hip_runtime.h>

// out[m,n] = Sx*Sy * ( dot_i8[m,n] - ZPy*rowsumX[m] - ZPx*colsumY[n] + K*ZPx*ZPy )
// ZP_X=-25, ZP_Y=18, K=4096  ->  const term = 4096*(-25)*18 = -1843200

typedef int v4i __attribute__((ext_vector_type(4)));

#define MDIM 4096
#define KDIM 4096
#define NDIM 4096

__device__ __forceinline__ void gload_lds16(const void* g, void* l) {
    __builtin_amdgcn_global_load_lds((const __attribute__((address_space(1))) void*)g,
                                     (__attribute__((address_space(3))) void*)l, 16, 0, 0);
}

// ---------------------------------------------------------------------------
// Pack X (int32 -> int8) into fragment-ordered tiles + rowsum.
// Packed A tile (mtile,ktile) is 8192B: byte p = ((mf*4+kg)*16 + r)*16 + t
//   holds x[mtile*128 + mf*16 + r][ktile*64 + kg*16 + t]
// ---------------------------------------------------------------------------
__global__ __launch_bounds__(256) void pack_a(const int* __restrict__ x,
                                              signed char* __restrict__ pA,
                                              int* __restrict__ rsX) {
    int f = blockIdx.x * 256 + threadIdx.x;      // [0, 4096*1024)
    int4 v = ((const int4*)x)[f];
    int k4 = (f << 2) & (KDIM - 1);              // k base (multiple of 4)
    int gm = f >> 10;                            // row
    int packed = (v.x & 255) | ((v.y & 255) << 8) | ((v.z & 255) << 16) | ((v.w & 255) << 24);
    int mtile = gm >> 7, mf = (gm >> 4) & 7, r = gm & 15;
    int ktile = k4 >> 6, kg = (k4 >> 4) & 3, t = k4 & 15;
    size_t off = ((size_t)(mtile * 64 + ktile)) * 8192 + (size_t)(((mf * 4 + kg) * 16 + r) * 16 + t);
    *(int*)(pA + off) = packed;
    // rowsum: one wave covers 256 consecutive k within a single row
    int s = v.x + v.y + v.z + v.w;
    #pragma unroll
    for (int d = 32; d; d >>= 1) s += __shfl_xor(s, d, 64);
    if ((threadIdx.x & 63) == 0) atomicAdd(&rsX[gm], s);
}

// ---------------------------------------------------------------------------
// Pack Y (int32 -> int8) with transpose into fragment-ordered tiles.
// Packed B tile (ntile,ktile) is 8192B: byte p = ((nf*4+kg)*16 + c)*16 + t
//   holds y[ktile*64 + kg*16 + t][ntile*128 + nf*16 + c]
// One block per output tile; LDS-staged transpose, coalesced 16B output.
// ---------------------------------------------------------------------------
__global__ __launch_bounds__(256) void pack_b(const int* __restrict__ y,
                                              signed char* __restrict__ pB) {
    __shared__ __align__(16) signed char tile[8192];
    int ntile = blockIdx.x >> 6;
    int ktile = blockIdx.x & 63;
    int n0 = ntile * 128, k0 = ktile * 64;
    int tid = threadIdx.x;
    int cq = tid & 31;       // which int4 within a row (cols cq*4..cq*4+3)
    int rr = tid >> 5;       // row within group of 8
    #pragma unroll
    for (int it = 0; it < 8; ++it) {
        int k = k0 + it * 8 + rr;
        int4 v = ((const int4*)(y + (size_t)k * NDIM + n0))[cq];
        int kg = (k >> 4) & 3, t = k & 15;
        int nc = cq * 4;
        int vals[4] = {v.x, v.y, v.z, v.w};
        #pragma unroll
        for (int j = 0; j < 4; ++j) {
            int nl = nc + j;
            int nf = nl >> 4, c = nl & 15;
            tile[((nf * 4 + kg) * 16 + c) * 16 + t] = (signed char)(vals[j] & 255);
        }
    }
    __syncthreads();
    size_t base = (size_t)blockIdx.x * 8192;
    ((int4*)(pB + base))[tid]       = ((const int4*)tile)[tid];
    ((int4*)(pB + base))[tid + 256] = ((const int4*)tile)[tid + 256];
}

// ---------------------------------------------------------------------------
// Column sums of y from packed B (16MB read, 32k atomics).
// grid = 32 ntiles * 4 kchunks
// ---------------------------------------------------------------------------
__device__ __forceinline__ int sbsum(int v) {
    return ((v << 24) >> 24) + ((v << 16) >> 24) + ((v << 8) >> 24) + (v >> 24);
}

__global__ __launch_bounds__(256) void colsum_b(const signed char* __restrict__ pB,
                                                int* __restrict__ csY) {
    int ntile = blockIdx.x >> 2;
    int kc = blockIdx.x & 3;                 // ktiles kc*16 .. kc*16+15
    int tid = threadIdx.x;
    int nl = tid & 127;
    int kgh = tid >> 7;                      // 0 -> kg{0,1}, 1 -> kg{2,3}
    int nf = nl >> 4, c = nl & 15;
    int sum = 0;
    for (int kt = 0; kt < 16; ++kt) {
        size_t tbase = (size_t)(ntile * 64 + kc * 16 + kt) * 8192;
        #pragma unroll
        for (int g = 0; g < 2; ++g) {
            int kg = kgh * 2 + g;
            v4i v = *(const v4i*)(pB + tbase + (size_t)(((nf * 4 + kg) * 16 + c) * 16));
            sum += sbsum(v.x) + sbsum(v.y) + sbsum(v.z) + sbsum(v.w);
        }
    }
    atomicAdd(&csY[ntile * 128 + nl], sum);
}

// ---------------------------------------------------------------------------
// i8 MFMA GEMM, m97 structure: 128x128 tile, 4 waves (2x2), BK=64,
// global_load_lds staging (linear: tiles are pre-packed in fragment order),
// fused dequant epilogue.
// ---------------------------------------------------------------------------
__global__ __launch_bounds__(256) void gemm_i8(const signed char* __restrict__ pA,
                                               const signed char* __restrict__ pB,
                                               const int* __restrict__ rsX,
                                               const int* __restrict__ csY,
                                               float* __restrict__ out) {
    __shared__ __align__(16) signed char ldsA[8192];
    __shared__ __align__(16) signed char ldsB[8192];
    const int bn = blockIdx.x, bm = blockIdx.y;
    const int tid = threadIdx.x;
    const int w = tid >> 6, lane = tid & 63;
    const int wr = w >> 1, wc = w & 1;

    v4i acc[4][4] = {};

    const signed char* gA = pA + (size_t)bm * 64 * 8192;
    const signed char* gB = pB + (size_t)bn * 64 * 8192;

    for (int kt = 0; kt < KDIM / 64; ++kt) {
        const signed char* a = gA + (size_t)kt * 8192;
        const signed char* b = gB + (size_t)kt * 8192;
        gload_lds16(a + tid * 16,        ldsA + tid * 16);
        gload_lds16(a + 4096 + tid * 16, ldsA + 4096 + tid * 16);
        gload_lds16(b + tid * 16,        ldsB + tid * 16);
        gload_lds16(b + 4096 + tid * 16, ldsB + 4096 + tid * 16);
        __syncthreads();   // drains vmcnt before barrier (compiler-enforced)

        v4i af[4], bf[4];
        #pragma unroll
        for (int i = 0; i < 4; ++i)
            af[i] = *(const v4i*)(ldsA + (wr * 4 + i) * 1024 + lane * 16);
        #pragma unroll
        for (int j = 0; j < 4; ++j)
            bf[j] = *(const v4i*)(ldsB + (wc * 4 + j) * 1024 + lane * 16);

        #pragma unroll
        for (int i = 0; i < 4; ++i)
            #pragma unroll
            for (int j = 0; j < 4; ++j)
                acc[i][j] = __builtin_amdgcn_mfma_i32_16x16x64_i8(af[i], bf[j], acc[i][j], 0, 0, 0);

        __syncthreads();
    }

    // epilogue: out = S * (dot - 18*rsX[m] + 25*csY[n] - 1843200)
    const float S = 0.0215f * 0.0176f;
    const int rbase = bm * 128 + wr * 64;
    const int cbase = bn * 128 + wc * 64;
    #pragma unroll
    for (int j = 0; j < 4; ++j) {
        const int col = cbase + j * 16 + (lane & 15);
        const int csv = 25 * csY[col] - 1843200;
        #pragma unroll
        for (int i = 0; i < 4; ++i) {
            #pragma unroll
            for (int q = 0; q < 4; ++q) {
                const int row = rbase + i * 16 + (lane >> 4) * 4 + q;
                const int t = acc[i][j][q] - 18 * rsX[row] + csv;
                out[(size_t)row * NDIM + col] = S * (float)t;
            }
        }
    }
}

// ---------------------------------------------------------------------------
extern "C" void kernel_launch(void* const* d_in, const int* in_sizes, int n_in,
                              void* d_out, int out_size, void* d_ws, size_t ws_size,
                              hipStream_t stream) {
    const int* x = (const int*)d_in[0];
    const int* y = (const int*)d_in[1];
    float* out = (float*)d_out;

    signed char* pA = (signed char*)d_ws;                       // 16 MB
    signed char* pB = pA + (size_t)(16u << 20);                 // 16 MB
    int* rsX = (int*)((char*)d_ws + (size_t)(32u << 20));       // 4096 int
    int* csY = rsX + 4096;                                      // 4096 int

    hipMemsetAsync(rsX, 0, 2 * 4096 * sizeof(int), stream);
    pack_a<<<MDIM * KDIM / 4 / 256, 256, 0, stream>>>(x, pA, rsX);
    pack_b<<<(NDIM / 128) * (KDIM / 64), 256, 0, stream>>>(y, pB);
    colsum_b<<<128, 256, 0, stream>>>(pB, csY);
    gemm_i8<<<dim3(NDIM / 128, MDIM / 128), 256, 0, stream>>>(pA, pB, rsX, csY, out);
}

// Round 4
// 263.726 us; speedup vs baseline: 1.0165x; 1.0165x over previous
//
#include <hip/hip_runtime.h>

// out[m,n] = Sx*Sy * ( dot_i8[m,n] - ZPy*rowsumX[m] - ZPx*colsumY[n] + K*ZPx*ZPy )
// ZP_X=-25, ZP_Y=18, K=4096  ->  const term = 4096*(-25)*18 = -1843200

typedef int v4i __attribute__((ext_vector_type(4)));

#define MDIM 4096
#define KDIM 4096
#define NDIM 4096

__device__ __forceinline__ void gload_lds16(const void* g, void* l) {
    __builtin_amdgcn_global_load_lds((const __attribute__((address_space(1))) void*)g,
                                     (__attribute__((address_space(3))) void*)l, 16, 0, 0);
}

__device__ __forceinline__ int pack4(int a, int b, int c, int d) {
    return (a & 255) | ((b & 255) << 8) | ((c & 255) << 16) | ((d & 255) << 24);
}

// ---------------------------------------------------------------------------
// Pack X (int32 -> int8) into fragment-ordered tiles + rowsum.
// Output 16B-fragment index o: tile = o>>9, frag = o&511 = (mf*4+kg)*16 + r.
// Fragment holds x[mtile*128+mf*16+r][ktile*64+kg*16 .. +15].
// Thread = one fragment: reads its 64B (4 x int4, one cache line), packs in
// registers, stores 16B coalesced (wave = contiguous 1KB). Rowsum via
// shfl_xor over the 4 lanes sharing r (kg=0..3), 16 atomics/wave.
// ---------------------------------------------------------------------------
__global__ __launch_bounds__(256) void pack_a(const int* __restrict__ x,
                                              signed char* __restrict__ pA,
                                              int* __restrict__ rsX) {
    int o = blockIdx.x * 256 + threadIdx.x;      // [0, 1M)
    int frag = o & 511;
    int tileIdx = o >> 9;
    int r = frag & 15;
    int kg = (frag >> 4) & 3;
    int mf = frag >> 6;
    int mtile = tileIdx >> 6, ktile = tileIdx & 63;
    int row = mtile * 128 + mf * 16 + r;
    int k0 = ktile * 64 + kg * 16;

    const int4* src = (const int4*)(x + (size_t)row * KDIM + k0);
    int out[4];
    int s = 0;
    #pragma unroll
    for (int i = 0; i < 4; ++i) {
        int4 v = src[i];
        out[i] = pack4(v.x, v.y, v.z, v.w);
        s += v.x + v.y + v.z + v.w;
    }
    *(int4*)(pA + (size_t)o * 16) = *(const int4*)out;

    // lanes {r, r+16, r+32, r+48} share `row` (base 64-aligned => kg = lane>>4)
    s += __shfl_xor(s, 16, 64);
    s += __shfl_xor(s, 32, 64);
    if ((threadIdx.x & 63) < 16) atomicAdd(&rsX[row], s);
}

// ---------------------------------------------------------------------------
// Pack Y (int32 -> int8) with transpose, in registers (no LDS).
// Output 16B-fragment index o: frag = (nf*4+kg)*16 + c holds
// y[ktile*64+kg*16 .. +15][ntile*128+nf*16+c].
// Thread gathers 16 k (strided rows) for one n; per load instruction the
// wave's 64 lanes read 4 contiguous 64B chunks (n is lane-fast). Stores
// 16B coalesced (wave = contiguous 1KB).
// ---------------------------------------------------------------------------
__global__ __launch_bounds__(256) void pack_b(const int* __restrict__ y,
                                              signed char* __restrict__ pB) {
    int o = blockIdx.x * 256 + threadIdx.x;      // [0, 1M)
    int frag = o & 511;
    int tileIdx = o >> 9;
    int c = frag & 15;
    int kg = (frag >> 4) & 3;
    int nf = frag >> 6;
    int ntile = tileIdx >> 6, ktile = tileIdx & 63;
    int n = ntile * 128 + nf * 16 + c;
    int k0 = ktile * 64 + kg * 16;

    const int* src = y + (size_t)k0 * NDIM + n;
    int out[4];
    #pragma unroll
    for (int g = 0; g < 4; ++g) {
        int b0 = src[(size_t)(g * 4 + 0) * NDIM];
        int b1 = src[(size_t)(g * 4 + 1) * NDIM];
        int b2 = src[(size_t)(g * 4 + 2) * NDIM];
        int b3 = src[(size_t)(g * 4 + 3) * NDIM];
        out[g] = pack4(b0, b1, b2, b3);
    }
    *(int4*)(pB + (size_t)o * 16) = *(const int4*)out;
}

// ---------------------------------------------------------------------------
// Column sums of y from packed B (16MB read, 32k atomics).
// grid = 32 ntiles * 4 kchunks
// ---------------------------------------------------------------------------
__device__ __forceinline__ int sbsum(int v) {
    return ((v << 24) >> 24) + ((v << 16) >> 24) + ((v << 8) >> 24) + (v >> 24);
}

__global__ __launch_bounds__(256) void colsum_b(const signed char* __restrict__ pB,
                                                int* __restrict__ csY) {
    int ntile = blockIdx.x >> 2;
    int kc = blockIdx.x & 3;                 // ktiles kc*16 .. kc*16+15
    int tid = threadIdx.x;
    int nl = tid & 127;
    int kgh = tid >> 7;                      // 0 -> kg{0,1}, 1 -> kg{2,3}
    int nf = nl >> 4, c = nl & 15;
    int sum = 0;
    for (int kt = 0; kt < 16; ++kt) {
        size_t tbase = (size_t)(ntile * 64 + kc * 16 + kt) * 8192;
        #pragma unroll
        for (int g = 0; g < 2; ++g) {
            int kg = kgh * 2 + g;
            v4i v = *(const v4i*)(pB + tbase + (size_t)(((nf * 4 + kg) * 16 + c) * 16));
            sum += sbsum(v.x) + sbsum(v.y) + sbsum(v.z) + sbsum(v.w);
        }
    }
    atomicAdd(&csY[ntile * 128 + nl], sum);
}

// ---------------------------------------------------------------------------
// i8 MFMA GEMM, m97 structure: 128x128 tile, 4 waves (2x2), BK=64,
// global_load_lds staging (linear: tiles are pre-packed in fragment order),
// fused dequant epilogue.  (unchanged from round 0 — baseline under test)
// ---------------------------------------------------------------------------
__global__ __launch_bounds__(256) void gemm_i8(const signed char* __restrict__ pA,
                                               const signed char* __restrict__ pB,
                                               const int* __restrict__ rsX,
                                               const int* __restrict__ csY,
                                               float* __restrict__ out) {
    __shared__ __align__(16) signed char ldsA[8192];
    __shared__ __align__(16) signed char ldsB[8192];
    const int bn = blockIdx.x, bm = blockIdx.y;
    const int tid = threadIdx.x;
    const int w = tid >> 6, lane = tid & 63;
    const int wr = w >> 1, wc = w & 1;

    v4i acc[4][4] = {};

    const signed char* gA = pA + (size_t)bm * 64 * 8192;
    const signed char* gB = pB + (size_t)bn * 64 * 8192;

    for (int kt = 0; kt < KDIM / 64; ++kt) {
        const signed char* a = gA + (size_t)kt * 8192;
        const signed char* b = gB + (size_t)kt * 8192;
        gload_lds16(a + tid * 16,        ldsA + tid * 16);
        gload_lds16(a + 4096 + tid * 16, ldsA + 4096 + tid * 16);
        gload_lds16(b + tid * 16,        ldsB + tid * 16);
        gload_lds16(b + 4096 + tid * 16, ldsB + 4096 + tid * 16);
        __syncthreads();   // drains vmcnt before barrier (compiler-enforced)

        v4i af[4], bf[4];
        #pragma unroll
        for (int i = 0; i < 4; ++i)
            af[i] = *(const v4i*)(ldsA + (wr * 4 + i) * 1024 + lane * 16);
        #pragma unroll
        for (int j = 0; j < 4; ++j)
            bf[j] = *(const v4i*)(ldsB + (wc * 4 + j) * 1024 + lane * 16);

        #pragma unroll
        for (int i = 0; i < 4; ++i)
            #pragma unroll
            for (int j = 0; j < 4; ++j)
                acc[i][j] = __builtin_amdgcn_mfma_i32_16x16x64_i8(af[i], bf[j], acc[i][j], 0, 0, 0);

        __syncthreads();
    }

    // epilogue: out = S * (dot - 18*rsX[m] + 25*csY[n] - 1843200)
    const float S = 0.0215f * 0.0176f;
    const int rbase = bm * 128 + wr * 64;
    const int cbase = bn * 128 + wc * 64;
    #pragma unroll
    for (int j = 0; j < 4; ++j) {
        const int col = cbase + j * 16 + (lane & 15);
        const int csv = 25 * csY[col] - 1843200;
        #pragma unroll
        for (int i = 0; i < 4; ++i) {
            #pragma unroll
            for (int q = 0; q < 4; ++q) {
                const int row = rbase + i * 16 + (lane >> 4) * 4 + q;
                const int t = acc[i][j][q] - 18 * rsX[row] + csv;
                out[(size_t)row * NDIM + col] = S * (float)t;
            }
        }
    }
}

// ---------------------------------------------------------------------------
extern "C" void kernel_launch(void* const* d_in, const int* in_sizes, int n_in,
                              void* d_out, int out_size, void* d_ws, size_t ws_size,
                              hipStream_t stream) {
    const int* x = (const int*)d_in[0];
    const int* y = (const int*)d_in[1];
    float* out = (float*)d_out;

    signed char* pA = (signed char*)d_ws;                       // 16 MB
    signed char* pB = pA + (size_t)(16u << 20);                 // 16 MB
    int* rsX = (int*)((char*)d_ws + (size_t)(32u << 20));       // 4096 int
    int* csY = rsX + 4096;                                      // 4096 int

    hipMemsetAsync(rsX, 0, 2 * 4096 * sizeof(int), stream);
    pack_a<<<MDIM * KDIM / 16 / 256, 256, 0, stream>>>(x, pA, rsX);
    pack_b<<<KDIM * NDIM / 16 / 256, 256, 0, stream>>>(y, pB);
    colsum_b<<<128, 256, 0, stream>>>(pB, csY);
    gemm_i8<<<dim3(NDIM / 128, MDIM / 128), 256, 0, stream>>>(pA, pB, rsX, csY, out);
}

// Round 5
// 254.312 us; speedup vs baseline: 1.0541x; 1.0370x over previous
//
#include <hip/hip_runtime.h>

// out[m,n] = Sx*Sy * ( dot_i8[m,n] - ZPy*rowsumX[m] - ZPx*colsumY[n] + K*ZPx*ZPy )
// ZP_X=-25, ZP_Y=18, K=4096  ->  const term = 4096*(-25)*18 = -1843200

typedef int v4i __attribute__((ext_vector_type(4)));

#define MDIM 4096
#define KDIM 4096
#define NDIM 4096

__device__ __forceinline__ void gload_lds16(const void* g, void* l) {
    __builtin_amdgcn_global_load_lds((const __attribute__((address_space(1))) void*)g,
                                     (__attribute__((address_space(3))) void*)l, 16, 0, 0);
}

__device__ __forceinline__ int pack4(int a, int b, int c, int d) {
    return (a & 255) | ((b & 255) << 8) | ((c & 255) << 16) | ((d & 255) << 24);
}

// ---------------------------------------------------------------------------
// Pack X (int32 -> int8) into fragment-ordered tiles + rowsum. (unchanged)
// ---------------------------------------------------------------------------
__global__ __launch_bounds__(256) void pack_a(const int* __restrict__ x,
                                              signed char* __restrict__ pA,
                                              int* __restrict__ rsX) {
    int o = blockIdx.x * 256 + threadIdx.x;      // [0, 1M)
    int frag = o & 511;
    int tileIdx = o >> 9;
    int r = frag & 15;
    int kg = (frag >> 4) & 3;
    int mf = frag >> 6;
    int mtile = tileIdx >> 6, ktile = tileIdx & 63;
    int row = mtile * 128 + mf * 16 + r;
    int k0 = ktile * 64 + kg * 16;

    const int4* src = (const int4*)(x + (size_t)row * KDIM + k0);
    int out[4];
    int s = 0;
    #pragma unroll
    for (int i = 0; i < 4; ++i) {
        int4 v = src[i];
        out[i] = pack4(v.x, v.y, v.z, v.w);
        s += v.x + v.y + v.z + v.w;
    }
    *(int4*)(pA + (size_t)o * 16) = *(const int4*)out;

    s += __shfl_xor(s, 16, 64);
    s += __shfl_xor(s, 32, 64);
    if ((threadIdx.x & 63) < 16) atomicAdd(&rsX[row], s);
}

// ---------------------------------------------------------------------------
// Pack Y (int32 -> int8) with transpose, in registers. (unchanged)
// ---------------------------------------------------------------------------
__global__ __launch_bounds__(256) void pack_b(const int* __restrict__ y,
                                              signed char* __restrict__ pB) {
    int o = blockIdx.x * 256 + threadIdx.x;      // [0, 1M)
    int frag = o & 511;
    int tileIdx = o >> 9;
    int c = frag & 15;
    int kg = (frag >> 4) & 3;
    int nf = frag >> 6;
    int ntile = tileIdx >> 6, ktile = tileIdx & 63;
    int n = ntile * 128 + nf * 16 + c;
    int k0 = ktile * 64 + kg * 16;

    const int* src = y + (size_t)k0 * NDIM + n;
    int out[4];
    #pragma unroll
    for (int g = 0; g < 4; ++g) {
        int b0 = src[(size_t)(g * 4 + 0) * NDIM];
        int b1 = src[(size_t)(g * 4 + 1) * NDIM];
        int b2 = src[(size_t)(g * 4 + 2) * NDIM];
        int b3 = src[(size_t)(g * 4 + 3) * NDIM];
        out[g] = pack4(b0, b1, b2, b3);
    }
    *(int4*)(pB + (size_t)o * 16) = *(const int4*)out;
}

// ---------------------------------------------------------------------------
// Column sums of y from packed B. (unchanged)
// ---------------------------------------------------------------------------
__device__ __forceinline__ int sbsum(int v) {
    return ((v << 24) >> 24) + ((v << 16) >> 24) + ((v << 8) >> 24) + (v >> 24);
}

__global__ __launch_bounds__(256) void colsum_b(const signed char* __restrict__ pB,
                                                int* __restrict__ csY) {
    int ntile = blockIdx.x >> 2;
    int kc = blockIdx.x & 3;
    int tid = threadIdx.x;
    int nl = tid & 127;
    int kgh = tid >> 7;
    int nf = nl >> 4, c = nl & 15;
    int sum = 0;
    for (int kt = 0; kt < 16; ++kt) {
        size_t tbase = (size_t)(ntile * 64 + kc * 16 + kt) * 8192;
        #pragma unroll
        for (int g = 0; g < 2; ++g) {
            int kg = kgh * 2 + g;
            v4i v = *(const v4i*)(pB + tbase + (size_t)(((nf * 4 + kg) * 16 + c) * 16));
            sum += sbsum(v.x) + sbsum(v.y) + sbsum(v.z) + sbsum(v.w);
        }
    }
    atomicAdd(&csY[ntile * 128 + nl], sum);
}

// ---------------------------------------------------------------------------
// i8 MFMA GEMM, 256x256 tile, 8 waves (2x4), BK=128, phase-pipelined
// (T3+T4+T5): 4 phases per K-tile, each {ds_read ∥ stage half-tile ->
// barrier -> lgkmcnt(0) -> 16 MFMA in setprio}. Counted vmcnt(2) once per
// iter, never drained. 128 KiB LDS double-buffer. Packed fragment-order
// tiles keep all staging linear and all ds_read_b128 conflict-free.
// ---------------------------------------------------------------------------
__global__ __launch_bounds__(512, 2) void gemm_i8(const signed char* __restrict__ pA,
                                                  const signed char* __restrict__ pB,
                                                  const int* __restrict__ rsX,
                                                  const int* __restrict__ csY,
                                                  float* __restrict__ out) {
    __shared__ __align__(16) signed char lds[131072];
    signed char* ldsA = lds;            // [buf][h][g][8192] : buf*32768 + h*16384 + g*8192
    signed char* ldsB = lds + 65536;

    const int bn = blockIdx.x, bm = blockIdx.y;
    const int tid = threadIdx.x;
    const int w = tid >> 6, lane = tid & 63;
    const int wr = w >> 2;               // 0..1 : A half (m)
    const int wc = w & 3;                // 0..3 : 64-col slice
    const int hb = wc >> 1;              // B half (n)
    const int nfl = (wc & 1) * 4;        // frag offset within B half
    const int lane16 = lane * 16;
    const int t16 = tid * 16;

    v4i acc[8][4] = {};

    // prologue: stage K-tile 0 into buf 0 (8 gloads/thread... 8 total ops: 4 pairs)
    #pragma unroll
    for (int h = 0; h < 2; ++h) {
        const signed char* sa = pA + ((size_t)((2 * bm + h) * 64)) * 8192 + t16;
        signed char* da = ldsA + h * 16384 + t16;
        gload_lds16(sa, da);
        gload_lds16(sa + 8192, da + 8192);
        const signed char* sb = pB + ((size_t)((2 * bn + h) * 64)) * 8192 + t16;
        signed char* db = ldsB + h * 16384 + t16;
        gload_lds16(sb, db);
        gload_lds16(sb + 8192, db + 8192);
    }

#define STAGE_A(H) do {                                                          \
        const signed char* s_ = pA + ((size_t)((2 * bm + (H)) * 64 + 2 * tn)) * 8192 + t16; \
        signed char* d_ = ldsA + nxt * 32768 + (H) * 16384 + t16;                \
        gload_lds16(s_, d_);                                                     \
        gload_lds16(s_ + 8192, d_ + 8192);                                       \
    } while (0)

#define STAGE_B(H) do {                                                          \
        const signed char* s_ = pB + ((size_t)((2 * bn + (H)) * 64 + 2 * tn)) * 8192 + t16; \
        signed char* d_ = ldsB + nxt * 32768 + (H) * 16384 + t16;                \
        gload_lds16(s_, d_);                                                     \
        gload_lds16(s_ + 8192, d_ + 8192);                                       \
    } while (0)

#define MFMA16(P, A0G0, A0G1, A1G0, A1G1)                                        \
    asm volatile("s_waitcnt lgkmcnt(0)" ::: "memory");                           \
    __builtin_amdgcn_sched_barrier(0);                                           \
    __builtin_amdgcn_s_setprio(1);                                               \
    _Pragma("unroll")                                                            \
    for (int nf = 0; nf < 4; ++nf) {                                             \
        acc[2*(P)][nf]   = __builtin_amdgcn_mfma_i32_16x16x64_i8(A0G0, bf[nf][0], acc[2*(P)][nf],   0, 0, 0); \
        acc[2*(P)][nf]   = __builtin_amdgcn_mfma_i32_16x16x64_i8(A0G1, bf[nf][1], acc[2*(P)][nf],   0, 0, 0); \
        acc[2*(P)+1][nf] = __builtin_amdgcn_mfma_i32_16x16x64_i8(A1G0, bf[nf][0], acc[2*(P)+1][nf], 0, 0, 0); \
        acc[2*(P)+1][nf] = __builtin_amdgcn_mfma_i32_16x16x64_i8(A1G1, bf[nf][1], acc[2*(P)+1][nf], 0, 0, 0); \
    }                                                                            \
    __builtin_amdgcn_s_setprio(0);                                               \
    __builtin_amdgcn_s_barrier();

    for (int t = 0; t < KDIM / 128; ++t) {
        const int cur = t & 1, nxt = cur ^ 1;
        const int tn = (t < KDIM / 128 - 1) ? t + 1 : t;   // last iter: harmless re-stage
        const signed char* La = ldsA + cur * 32768 + wr * 16384 + lane16;
        const signed char* Lb = ldsB + cur * 32768 + hb * 16384 + nfl * 1024 + lane16;

        // ---- phase 0: stage A-h0(next); wait tile t resident; read B(all)+A(0,1)
        STAGE_A(0);
        asm volatile("s_waitcnt vmcnt(2)" ::: "memory");
        __builtin_amdgcn_s_barrier();
        __builtin_amdgcn_sched_barrier(0);
        v4i bf[4][2];
        #pragma unroll
        for (int nf = 0; nf < 4; ++nf) {
            bf[nf][0] = *(const v4i*)(Lb + nf * 1024);
            bf[nf][1] = *(const v4i*)(Lb + nf * 1024 + 8192);
        }
        {
            v4i a0g0 = *(const v4i*)(La + 0 * 1024);
            v4i a0g1 = *(const v4i*)(La + 0 * 1024 + 8192);
            v4i a1g0 = *(const v4i*)(La + 1 * 1024);
            v4i a1g1 = *(const v4i*)(La + 1 * 1024 + 8192);
            MFMA16(0, a0g0, a0g1, a1g0, a1g1)
        }

        // ---- phase 1: read A(2,3); stage A-h1(next)
        {
            v4i a0g0 = *(const v4i*)(La + 2 * 1024);
            v4i a0g1 = *(const v4i*)(La + 2 * 1024 + 8192);
            v4i a1g0 = *(const v4i*)(La + 3 * 1024);
            v4i a1g1 = *(const v4i*)(La + 3 * 1024 + 8192);
            STAGE_A(1);
            __builtin_amdgcn_s_barrier();
            MFMA16(1, a0g0, a0g1, a1g0, a1g1)
        }

        // ---- phase 2: read A(4,5); stage B-h0(next)
        {
            v4i a0g0 = *(const v4i*)(La + 4 * 1024);
            v4i a0g1 = *(const v4i*)(La + 4 * 1024 + 8192);
            v4i a1g0 = *(const v4i*)(La + 5 * 1024);
            v4i a1g1 = *(const v4i*)(La + 5 * 1024 + 8192);
            STAGE_B(0);
            __builtin_amdgcn_s_barrier();
            MFMA16(2, a0g0, a0g1, a1g0, a1g1)
        }

        // ---- phase 3: read A(6,7); stage B-h1(next)
        {
            v4i a0g0 = *(const v4i*)(La + 6 * 1024);
            v4i a0g1 = *(const v4i*)(La + 6 * 1024 + 8192);
            v4i a1g0 = *(const v4i*)(La + 7 * 1024);
            v4i a1g1 = *(const v4i*)(La + 7 * 1024 + 8192);
            STAGE_B(1);
            __builtin_amdgcn_s_barrier();
            MFMA16(3, a0g0, a0g1, a1g0, a1g1)
        }
    }

    // epilogue: out = S * (dot - 18*rsX[m] + 25*csY[n] - 1843200)
    const float S = 0.0215f * 0.0176f;
    const int rbase = bm * 256 + wr * 128;
    const int cbase = bn * 256 + wc * 64;
    #pragma unroll
    for (int nf = 0; nf < 4; ++nf) {
        const int col = cbase + nf * 16 + (lane & 15);
        const int csv = 25 * csY[col] - 1843200;
        #pragma unroll
        for (int mf = 0; mf < 8; ++mf) {
            #pragma unroll
            for (int q = 0; q < 4; ++q) {
                const int row = rbase + mf * 16 + (lane >> 4) * 4 + q;
                const int tv = acc[mf][nf][q] - 18 * rsX[row] + csv;
                out[(size_t)row * NDIM + col] = S * (float)tv;
            }
        }
    }
#undef STAGE_A
#undef STAGE_B
#undef MFMA16
}

// ---------------------------------------------------------------------------
extern "C" void kernel_launch(void* const* d_in, const int* in_sizes, int n_in,
                              void* d_out, int out_size, void* d_ws, size_t ws_size,
                              hipStream_t stream) {
    const int* x = (const int*)d_in[0];
    const int* y = (const int*)d_in[1];
    float* out = (float*)d_out;

    signed char* pA = (signed char*)d_ws;                       // 16 MB
    signed char* pB = pA + (size_t)(16u << 20);                 // 16 MB
    int* rsX = (int*)((char*)d_ws + (size_t)(32u << 20));       // 4096 int
    int* csY = rsX + 4096;                                      // 4096 int

    hipMemsetAsync(rsX, 0, 2 * 4096 * sizeof(int), stream);
    pack_a<<<MDIM * KDIM / 16 / 256, 256, 0, stream>>>(x, pA, rsX);
    pack_b<<<KDIM * NDIM / 16 / 256, 256, 0, stream>>>(y, pB);
    colsum_b<<<128, 256, 0, stream>>>(pB, csY);
    gemm_i8<<<dim3(NDIM / 256, MDIM / 256), 512, 0, stream>>>(pA, pB, rsX, csY, out);
}

// Round 7
// 249.796 us; speedup vs baseline: 1.0732x; 1.0181x over previous
//
#include <hip/hip_runtime.h>

// out[m,n] = Sx*Sy * ( dot_i8[m,n] - ZPy*rowsumX[m] - ZPx*colsumY[n] + K*ZPx*ZPy )
// ZP_X=-25, ZP_Y=18, K=4096  ->  const term = 4096*(-25)*18 = -1843200

typedef int v4i  __attribute__((ext_vector_type(4)));
typedef int v16i __attribute__((ext_vector_type(16)));

#define MDIM 4096
#define KDIM 4096
#define NDIM 4096

__device__ __forceinline__ void gload_lds16(const void* g, void* l) {
    __builtin_amdgcn_global_load_lds((const __attribute__((address_space(1))) void*)g,
                                     (__attribute__((address_space(3))) void*)l, 16, 0, 0);
}

__device__ __forceinline__ int pack4(int a, int b, int c, int d) {
    return (a & 255) | ((b & 255) << 8) | ((c & 255) << 16) | ((d & 255) << 24);
}

// ---------------------------------------------------------------------------
// Pack X (int32 -> int8) into fragment-ordered tiles + rowsum. (unchanged)
// ---------------------------------------------------------------------------
__global__ __launch_bounds__(256) void pack_a(const int* __restrict__ x,
                                              signed char* __restrict__ pA,
                                              int* __restrict__ rsX) {
    int o = blockIdx.x * 256 + threadIdx.x;      // [0, 1M)
    int frag = o & 511;
    int tileIdx = o >> 9;
    int r = frag & 15;
    int kg = (frag >> 4) & 3;
    int mf = frag >> 6;
    int mtile = tileIdx >> 6, ktile = tileIdx & 63;
    int row = mtile * 128 + mf * 16 + r;
    int k0 = ktile * 64 + kg * 16;

    const int4* src = (const int4*)(x + (size_t)row * KDIM + k0);
    int out[4];
    int s = 0;
    #pragma unroll
    for (int i = 0; i < 4; ++i) {
        int4 v = src[i];
        out[i] = pack4(v.x, v.y, v.z, v.w);
        s += v.x + v.y + v.z + v.w;
    }
    *(int4*)(pA + (size_t)o * 16) = *(const int4*)out;

    s += __shfl_xor(s, 16, 64);
    s += __shfl_xor(s, 32, 64);
    if ((threadIdx.x & 63) < 16) atomicAdd(&rsX[row], s);
}

// ---------------------------------------------------------------------------
// Pack Y (int32 -> int8) with transpose, in registers. (unchanged)
// ---------------------------------------------------------------------------
__global__ __launch_bounds__(256) void pack_b(const int* __restrict__ y,
                                              signed char* __restrict__ pB) {
    int o = blockIdx.x * 256 + threadIdx.x;      // [0, 1M)
    int frag = o & 511;
    int tileIdx = o >> 9;
    int c = frag & 15;
    int kg = (frag >> 4) & 3;
    int nf = frag >> 6;
    int ntile = tileIdx >> 6, ktile = tileIdx & 63;
    int n = ntile * 128 + nf * 16 + c;
    int k0 = ktile * 64 + kg * 16;

    const int* src = y + (size_t)k0 * NDIM + n;
    int out[4];
    #pragma unroll
    for (int g = 0; g < 4; ++g) {
        int b0 = src[(size_t)(g * 4 + 0) * NDIM];
        int b1 = src[(size_t)(g * 4 + 1) * NDIM];
        int b2 = src[(size_t)(g * 4 + 2) * NDIM];
        int b3 = src[(size_t)(g * 4 + 3) * NDIM];
        out[g] = pack4(b0, b1, b2, b3);
    }
    *(int4*)(pB + (size_t)o * 16) = *(const int4*)out;
}

// ---------------------------------------------------------------------------
// Column sums of y from packed B. (unchanged)
// ---------------------------------------------------------------------------
__device__ __forceinline__ int sbsum(int v) {
    return ((v << 24) >> 24) + ((v << 16) >> 24) + ((v << 8) >> 24) + (v >> 24);
}

__global__ __launch_bounds__(256) void colsum_b(const signed char* __restrict__ pB,
                                                int* __restrict__ csY) {
    int ntile = blockIdx.x >> 2;
    int kc = blockIdx.x & 3;
    int tid = threadIdx.x;
    int nl = tid & 127;
    int kgh = tid >> 7;
    int nf = nl >> 4, c = nl & 15;
    int sum = 0;
    for (int kt = 0; kt < 16; ++kt) {
        size_t tbase = (size_t)(ntile * 64 + kc * 16 + kt) * 8192;
        #pragma unroll
        for (int g = 0; g < 2; ++g) {
            int kg = kgh * 2 + g;
            v4i v = *(const v4i*)(pB + tbase + (size_t)(((nf * 4 + kg) * 16 + c) * 16));
            sum += sbsum(v.x) + sbsum(v.y) + sbsum(v.z) + sbsum(v.w);
        }
    }
    atomicAdd(&csY[ntile * 128 + nl], sum);
}

// ---------------------------------------------------------------------------
// i8 MFMA GEMM, 256x256 tile, 8 waves (2x4), BK=128, 32x32x32 MFMA.
// Phase-pipelined (T3+T4+T5): 4 phases per K-tile, phase = one k-step of 32:
// {6 ds_read (4 A + 2 B) ∥ stage half-tile -> barrier -> lgkmcnt(0) ->
// 8 MFMA in setprio -> barrier}. Counted vmcnt(2) once per iter.
// K-step byte offsets within a staged half: ks 0,1 live in the first packed
// 8192B sub-tile (kg*256 = 0,512); ks 2,3 in the second at +8192 (8192,8704).
// (Round-6 bug was ks*512 for all — wrong bytes for half the K.)
// ---------------------------------------------------------------------------
__global__ __launch_bounds__(512, 2) void gemm_i8(const signed char* __restrict__ pA,
                                                  const signed char* __restrict__ pB,
                                                  const int* __restrict__ rsX,
                                                  const int* __restrict__ csY,
                                                  float* __restrict__ out) {
    __shared__ __align__(16) signed char lds[131072];
    signed char* ldsA = lds;            // [buf][h][2 x 8192B sub-tiles]
    signed char* ldsB = lds + 65536;

    const int bn = blockIdx.x, bm = blockIdx.y;
    const int tid = threadIdx.x;
    const int w = tid >> 6, lane = tid & 63;
    const int wr = w >> 2;               // 0..1 : A half (128 rows)
    const int wc = w & 3;                // 0..3 : 64-col slice
    const int hb = wc >> 1;              // B half
    const int nfb = (wc & 1) * 4;        // nf16 base within B half
    const int t16 = tid * 16;

    // per-lane offset inside a 32-row fragment (row = lane&31, k-parity = lane>>5):
    // mf parity ((lane>>4)&1)*1024 + kg parity (lane>>5)*256 + r*16
    const int foff = ((lane >> 4) & 1) * 1024 + (lane >> 5) * 256 + (lane & 15) * 16;

    v16i acc[4][2] = {};

    // prologue: stage K-tile 0 into buf 0
    #pragma unroll
    for (int h = 0; h < 2; ++h) {
        const signed char* sa = pA + ((size_t)((2 * bm + h) * 64)) * 8192 + t16;
        signed char* da = ldsA + h * 16384 + t16;
        gload_lds16(sa, da);
        gload_lds16(sa + 8192, da + 8192);
        const signed char* sb = pB + ((size_t)((2 * bn + h) * 64)) * 8192 + t16;
        signed char* db = ldsB + h * 16384 + t16;
        gload_lds16(sb, db);
        gload_lds16(sb + 8192, db + 8192);
    }

#define STAGE_A(H) do {                                                          \
        const signed char* s_ = pA + ((size_t)((2 * bm + (H)) * 64 + 2 * tn)) * 8192 + t16; \
        signed char* d_ = ldsA + nxt * 32768 + (H) * 16384 + t16;                \
        gload_lds16(s_, d_);                                                     \
        gload_lds16(s_ + 8192, d_ + 8192);                                       \
    } while (0)

#define STAGE_B(H) do {                                                          \
        const signed char* s_ = pB + ((size_t)((2 * bn + (H)) * 64 + 2 * tn)) * 8192 + t16; \
        signed char* d_ = ldsB + nxt * 32768 + (H) * 16384 + t16;                \
        gload_lds16(s_, d_);                                                     \
        gload_lds16(s_ + 8192, d_ + 8192);                                       \
    } while (0)

#define READS(KOFS)                                                              \
    v4i af0 = *(const v4i*)(La + 0 * 2048 + (KOFS));                             \
    v4i af1 = *(const v4i*)(La + 1 * 2048 + (KOFS));                             \
    v4i af2 = *(const v4i*)(La + 2 * 2048 + (KOFS));                             \
    v4i af3 = *(const v4i*)(La + 3 * 2048 + (KOFS));                             \
    v4i bf0 = *(const v4i*)(Lb + 0 * 2048 + (KOFS));                             \
    v4i bf1 = *(const v4i*)(Lb + 1 * 2048 + (KOFS));

#define MFMA8()                                                                  \
    asm volatile("s_waitcnt lgkmcnt(0)" ::: "memory");                           \
    __builtin_amdgcn_sched_barrier(0);                                           \
    __builtin_amdgcn_s_setprio(1);                                               \
    acc[0][0] = __builtin_amdgcn_mfma_i32_32x32x32_i8(af0, bf0, acc[0][0], 0, 0, 0); \
    acc[1][0] = __builtin_amdgcn_mfma_i32_32x32x32_i8(af1, bf0, acc[1][0], 0, 0, 0); \
    acc[2][0] = __builtin_amdgcn_mfma_i32_32x32x32_i8(af2, bf0, acc[2][0], 0, 0, 0); \
    acc[3][0] = __builtin_amdgcn_mfma_i32_32x32x32_i8(af3, bf0, acc[3][0], 0, 0, 0); \
    acc[0][1] = __builtin_amdgcn_mfma_i32_32x32x32_i8(af0, bf1, acc[0][1], 0, 0, 0); \
    acc[1][1] = __builtin_amdgcn_mfma_i32_32x32x32_i8(af1, bf1, acc[1][1], 0, 0, 0); \
    acc[2][1] = __builtin_amdgcn_mfma_i32_32x32x32_i8(af2, bf1, acc[2][1], 0, 0, 0); \
    acc[3][1] = __builtin_amdgcn_mfma_i32_32x32x32_i8(af3, bf1, acc[3][1], 0, 0, 0); \
    __builtin_amdgcn_s_setprio(0);                                               \
    __builtin_amdgcn_s_barrier();

    for (int t = 0; t < KDIM / 128; ++t) {
        const int cur = t & 1, nxt = cur ^ 1;
        const int tn = (t < KDIM / 128 - 1) ? t + 1 : t;   // last iter: harmless re-stage
        const signed char* La = ldsA + cur * 32768 + wr * 16384 + foff;
        const signed char* Lb = ldsB + cur * 32768 + hb * 16384 + nfb * 1024 + foff;

        // ---- phase 0 (k 0..31): stage A-h0(next); wait tile t resident
        {
            STAGE_A(0);
            asm volatile("s_waitcnt vmcnt(2)" ::: "memory");
            __builtin_amdgcn_s_barrier();
            __builtin_amdgcn_sched_barrier(0);
            READS(0)
            MFMA8()
        }
        // ---- phase 1 (k 32..63): stage A-h1(next)
        {
            READS(512)
            STAGE_A(1);
            __builtin_amdgcn_s_barrier();
            MFMA8()
        }
        // ---- phase 2 (k 64..95, second sub-tile): stage B-h0(next)
        {
            READS(8192)
            STAGE_B(0);
            __builtin_amdgcn_s_barrier();
            MFMA8()
        }
        // ---- phase 3 (k 96..127): stage B-h1(next)
        {
            READS(8704)
            STAGE_B(1);
            __builtin_amdgcn_s_barrier();
            MFMA8()
        }
    }

    // epilogue: out = S * (dot - 18*rsX[m] + 25*csY[n] - 1843200)
    // 32x32 C/D layout: col = lane&31, row = (reg&3) + 8*(reg>>2) + 4*(lane>>5)
    const float S = 0.0215f * 0.0176f;
    const int rbase = bm * 256 + wr * 128;
    const int cbase = bn * 256 + wc * 64;
    const int lrow = 4 * (lane >> 5);
    const int lcol = lane & 31;
    #pragma unroll
    for (int nj = 0; nj < 2; ++nj) {
        const int col = cbase + nj * 32 + lcol;
        const int csv = 25 * csY[col] - 1843200;
        #pragma unroll
        for (int mj = 0; mj < 4; ++mj) {
            #pragma unroll
            for (int reg = 0; reg < 16; ++reg) {
                const int row = rbase + mj * 32 + (reg & 3) + 8 * (reg >> 2) + lrow;
                const int tv = acc[mj][nj][reg] - 18 * rsX[row] + csv;
                out[(size_t)row * NDIM + col] = S * (float)tv;
            }
        }
    }
#undef STAGE_A
#undef STAGE_B
#undef READS
#undef MFMA8
}

// ---------------------------------------------------------------------------
extern "C" void kernel_launch(void* const* d_in, const int* in_sizes, int n_in,
                              void* d_out, int out_size, void* d_ws, size_t ws_size,
                              hipStream_t stream) {
    const int* x = (const int*)d_in[0];
    const int* y = (const int*)d_in[1];
    float* out = (float*)d_out;

    signed char* pA = (signed char*)d_ws;                       // 16 MB
    signed char* pB = pA + (size_t)(16u << 20);                 // 16 MB
    int* rsX = (int*)((char*)d_ws + (size_t)(32u << 20));       // 4096 int
    int* csY = rsX + 4096;                                      // 4096 int

    hipMemsetAsync(rsX, 0, 2 * 4096 * sizeof(int), stream);
    pack_a<<<MDIM * KDIM / 16 / 256, 256, 0, stream>>>(x, pA, rsX);
    pack_b<<<KDIM * NDIM / 16 / 256, 256, 0, stream>>>(y, pB);
    colsum_b<<<128, 256, 0, stream>>>(pB, csY);
    gemm_i8<<<dim3(NDIM / 256, MDIM / 256), 512, 0, stream>>>(pA, pB, rsX, csY, out);
}

// Round 8
// 247.685 us; speedup vs baseline: 1.0823x; 1.0085x over previous
//
#include <hip/hip_runtime.h>

// out[m,n] = Sx*Sy * ( dot_i8[m,n] - ZPy*rowsumX[m] - ZPx*colsumY[n] + K*ZPx*ZPy )
// ZP_X=-25, ZP_Y=18, K=4096  ->  const term = 4096*(-25)*18 = -1843200

typedef int v4i  __attribute__((ext_vector_type(4)));
typedef int v16i __attribute__((ext_vector_type(16)));

#define MDIM 4096
#define KDIM 4096
#define NDIM 4096

__device__ __forceinline__ void gload_lds16(const void* g, void* l) {
    __builtin_amdgcn_global_load_lds((const __attribute__((address_space(1))) void*)g,
                                     (__attribute__((address_space(3))) void*)l, 16, 0, 0);
}

__device__ __forceinline__ int pack4(int a, int b, int c, int d) {
    return (a & 255) | ((b & 255) << 8) | ((c & 255) << 16) | ((d & 255) << 24);
}

// ---------------------------------------------------------------------------
// Pack X (int32 -> int8) into fragment-ordered tiles + rowsum. (unchanged)
// ---------------------------------------------------------------------------
__global__ __launch_bounds__(256) void pack_a(const int* __restrict__ x,
                                              signed char* __restrict__ pA,
                                              int* __restrict__ rsX) {
    int o = blockIdx.x * 256 + threadIdx.x;      // [0, 1M)
    int frag = o & 511;
    int tileIdx = o >> 9;
    int r = frag & 15;
    int kg = (frag >> 4) & 3;
    int mf = frag >> 6;
    int mtile = tileIdx >> 6, ktile = tileIdx & 63;
    int row = mtile * 128 + mf * 16 + r;
    int k0 = ktile * 64 + kg * 16;

    const int4* src = (const int4*)(x + (size_t)row * KDIM + k0);
    int out[4];
    int s = 0;
    #pragma unroll
    for (int i = 0; i < 4; ++i) {
        int4 v = src[i];
        out[i] = pack4(v.x, v.y, v.z, v.w);
        s += v.x + v.y + v.z + v.w;
    }
    *(int4*)(pA + (size_t)o * 16) = *(const int4*)out;

    s += __shfl_xor(s, 16, 64);
    s += __shfl_xor(s, 32, 64);
    if ((threadIdx.x & 63) < 16) atomicAdd(&rsX[row], s);
}

// ---------------------------------------------------------------------------
// Pack Y (int32 -> int8) with transpose, in registers. (unchanged)
// ---------------------------------------------------------------------------
__global__ __launch_bounds__(256) void pack_b(const int* __restrict__ y,
                                              signed char* __restrict__ pB) {
    int o = blockIdx.x * 256 + threadIdx.x;      // [0, 1M)
    int frag = o & 511;
    int tileIdx = o >> 9;
    int c = frag & 15;
    int kg = (frag >> 4) & 3;
    int nf = frag >> 6;
    int ntile = tileIdx >> 6, ktile = tileIdx & 63;
    int n = ntile * 128 + nf * 16 + c;
    int k0 = ktile * 64 + kg * 16;

    const int* src = y + (size_t)k0 * NDIM + n;
    int out[4];
    #pragma unroll
    for (int g = 0; g < 4; ++g) {
        int b0 = src[(size_t)(g * 4 + 0) * NDIM];
        int b1 = src[(size_t)(g * 4 + 1) * NDIM];
        int b2 = src[(size_t)(g * 4 + 2) * NDIM];
        int b3 = src[(size_t)(g * 4 + 3) * NDIM];
        out[g] = pack4(b0, b1, b2, b3);
    }
    *(int4*)(pB + (size_t)o * 16) = *(const int4*)out;
}

// ---------------------------------------------------------------------------
// Column sums of y from packed B. (unchanged)
// ---------------------------------------------------------------------------
__device__ __forceinline__ int sbsum(int v) {
    return ((v << 24) >> 24) + ((v << 16) >> 24) + ((v << 8) >> 24) + (v >> 24);
}

__global__ __launch_bounds__(256) void colsum_b(const signed char* __restrict__ pB,
                                                int* __restrict__ csY) {
    int ntile = blockIdx.x >> 2;
    int kc = blockIdx.x & 3;
    int tid = threadIdx.x;
    int nl = tid & 127;
    int kgh = tid >> 7;
    int nf = nl >> 4, c = nl & 15;
    int sum = 0;
    for (int kt = 0; kt < 16; ++kt) {
        size_t tbase = (size_t)(ntile * 64 + kc * 16 + kt) * 8192;
        #pragma unroll
        for (int g = 0; g < 2; ++g) {
            int kg = kgh * 2 + g;
            v4i v = *(const v4i*)(pB + tbase + (size_t)(((nf * 4 + kg) * 16 + c) * 16));
            sum += sbsum(v.x) + sbsum(v.y) + sbsum(v.z) + sbsum(v.w);
        }
    }
    atomicAdd(&csY[ntile * 128 + nl], sum);
}

// ---------------------------------------------------------------------------
// i8 MFMA GEMM, 256x256 tile, 8 waves (2x4), BK=128, 32x32x32 MFMA.
// Round-8 structure: 2 barriers + 1 counted vmcnt per K-iter (was 8 barriers).
// Hazards: barrier#1 = all waves done reading buffer `nxt` (read in t-1);
// barrier#2 (after per-wave vmcnt(8)) = this iter's `cur` staging resident
// for all waves. Within the iter: no read/write hazard (reads hit cur,
// stages write nxt) -> reads pipelined one k-step ahead with dual register
// sets; compiler emits counted lgkmcnt from visible reg deps.
// ---------------------------------------------------------------------------
__global__ __launch_bounds__(512, 2) void gemm_i8(const signed char* __restrict__ pA,
                                                  const signed char* __restrict__ pB,
                                                  const int* __restrict__ rsX,
                                                  const int* __restrict__ csY,
                                                  float* __restrict__ out) {
    __shared__ __align__(16) signed char lds[131072];
    signed char* ldsA = lds;            // [buf][h][2 x 8192B sub-tiles]
    signed char* ldsB = lds + 65536;

    const int bn = blockIdx.x, bm = blockIdx.y;
    const int tid = threadIdx.x;
    const int w = tid >> 6, lane = tid & 63;
    const int wr = w >> 2;               // 0..1 : A half (128 rows)
    const int wc = w & 3;                // 0..3 : 64-col slice
    const int hb = wc >> 1;              // B half
    const int nfb = (wc & 1) * 4;        // nf16 base within B half
    const int t16 = tid * 16;

    // per-lane offset inside a 32-row fragment (row = lane&31, k-parity = lane>>5)
    const int foff = ((lane >> 4) & 1) * 1024 + (lane >> 5) * 256 + (lane & 15) * 16;

    v16i acc[4][2] = {};

    // prologue: stage K-tile 0 into buf 0
    #pragma unroll
    for (int h = 0; h < 2; ++h) {
        const signed char* sa = pA + ((size_t)((2 * bm + h) * 64)) * 8192 + t16;
        signed char* da = ldsA + h * 16384 + t16;
        gload_lds16(sa, da);
        gload_lds16(sa + 8192, da + 8192);
        const signed char* sb = pB + ((size_t)((2 * bn + h) * 64)) * 8192 + t16;
        signed char* db = ldsB + h * 16384 + t16;
        gload_lds16(sb, db);
        gload_lds16(sb + 8192, db + 8192);
    }

#define STAGE_A(H) do {                                                          \
        const signed char* s_ = pA + ((size_t)((2 * bm + (H)) * 64 + 2 * tn)) * 8192 + t16; \
        signed char* d_ = ldsA + nxt * 32768 + (H) * 16384 + t16;                \
        gload_lds16(s_, d_);                                                     \
        gload_lds16(s_ + 8192, d_ + 8192);                                       \
    } while (0)

#define STAGE_B(H) do {                                                          \
        const signed char* s_ = pB + ((size_t)((2 * bn + (H)) * 64 + 2 * tn)) * 8192 + t16; \
        signed char* d_ = ldsB + nxt * 32768 + (H) * 16384 + t16;                \
        gload_lds16(s_, d_);                                                     \
        gload_lds16(s_ + 8192, d_ + 8192);                                       \
    } while (0)

// dual register sets: S in {A,B}; k-step offsets 0,512 (sub-tile 0) and
// 8192,8704 (sub-tile 1)
#define READS(S, KOFS)                                                           \
    a##S##0 = *(const v4i*)(La + 0 * 2048 + (KOFS));                             \
    a##S##1 = *(const v4i*)(La + 1 * 2048 + (KOFS));                             \
    a##S##2 = *(const v4i*)(La + 2 * 2048 + (KOFS));                             \
    a##S##3 = *(const v4i*)(La + 3 * 2048 + (KOFS));                             \
    b##S##0 = *(const v4i*)(Lb + 0 * 2048 + (KOFS));                             \
    b##S##1 = *(const v4i*)(Lb + 1 * 2048 + (KOFS));

#define MFMA8(S)                                                                 \
    __builtin_amdgcn_s_setprio(1);                                               \
    acc[0][0] = __builtin_amdgcn_mfma_i32_32x32x32_i8(a##S##0, b##S##0, acc[0][0], 0, 0, 0); \
    acc[1][0] = __builtin_amdgcn_mfma_i32_32x32x32_i8(a##S##1, b##S##0, acc[1][0], 0, 0, 0); \
    acc[2][0] = __builtin_amdgcn_mfma_i32_32x32x32_i8(a##S##2, b##S##0, acc[2][0], 0, 0, 0); \
    acc[3][0] = __builtin_amdgcn_mfma_i32_32x32x32_i8(a##S##3, b##S##0, acc[3][0], 0, 0, 0); \
    acc[0][1] = __builtin_amdgcn_mfma_i32_32x32x32_i8(a##S##0, b##S##1, acc[0][1], 0, 0, 0); \
    acc[1][1] = __builtin_amdgcn_mfma_i32_32x32x32_i8(a##S##1, b##S##1, acc[1][1], 0, 0, 0); \
    acc[2][1] = __builtin_amdgcn_mfma_i32_32x32x32_i8(a##S##2, b##S##1, acc[2][1], 0, 0, 0); \
    acc[3][1] = __builtin_amdgcn_mfma_i32_32x32x32_i8(a##S##3, b##S##1, acc[3][1], 0, 0, 0); \
    __builtin_amdgcn_s_setprio(0);

    v4i aA0, aA1, aA2, aA3, bA0, bA1;
    v4i aB0, aB1, aB2, aB3, bB0, bB1;

    for (int t = 0; t < KDIM / 128; ++t) {
        const int cur = t & 1, nxt = cur ^ 1;
        const int tn = (t < KDIM / 128 - 1) ? t + 1 : t;   // last iter: harmless re-stage
        const signed char* La = ldsA + cur * 32768 + wr * 16384 + foff;
        const signed char* Lb = ldsB + cur * 32768 + hb * 16384 + nfb * 1024 + foff;

        // barrier #1: all waves finished reading buffer `nxt` in iter t-1
        __builtin_amdgcn_s_barrier();
        __builtin_amdgcn_sched_barrier(0);

        // stage K-tile t+1 into nxt (8 global_load_lds)
        STAGE_A(0); STAGE_A(1); STAGE_B(0); STAGE_B(1);

        // my 8 loads from iter t-1 (into cur) are the oldest in flight
        asm volatile("s_waitcnt vmcnt(8)" ::: "memory");
        __builtin_amdgcn_sched_barrier(0);
        // barrier #2: everyone's cur-staging resident
        __builtin_amdgcn_s_barrier();
        __builtin_amdgcn_sched_barrier(0);

        // pipelined compute: reads run one k-step ahead of MFMA
        READS(A, 0)
        READS(B, 512)
        MFMA8(A)                 // ks0  (compiler inserts counted lgkmcnt)
        READS(A, 8192)
        MFMA8(B)                 // ks1
        READS(B, 8704)
        MFMA8(A)                 // ks2
        MFMA8(B)                 // ks3
    }

    // epilogue: out = S * (dot - 18*rsX[m] + 25*csY[n] - 1843200)
    // 32x32 C/D layout: col = lane&31, row = (reg&3) + 8*(reg>>2) + 4*(lane>>5)
    const float S = 0.0215f * 0.0176f;
    const int rbase = bm * 256 + wr * 128;
    const int cbase = bn * 256 + wc * 64;
    const int lrow = 4 * (lane >> 5);
    const int lcol = lane & 31;
    #pragma unroll
    for (int nj = 0; nj < 2; ++nj) {
        const int col = cbase + nj * 32 + lcol;
        const int csv = 25 * csY[col] - 1843200;
        #pragma unroll
        for (int mj = 0; mj < 4; ++mj) {
            #pragma unroll
            for (int reg = 0; reg < 16; ++reg) {
                const int row = rbase + mj * 32 + (reg & 3) + 8 * (reg >> 2) + lrow;
                const int tv = acc[mj][nj][reg] - 18 * rsX[row] + csv;
                out[(size_t)row * NDIM + col] = S * (float)tv;
            }
        }
    }
#undef STAGE_A
#undef STAGE_B
#undef READS
#undef MFMA8
}

// ---------------------------------------------------------------------------
extern "C" void kernel_launch(void* const* d_in, const int* in_sizes, int n_in,
                              void* d_out, int out_size, void* d_ws, size_t ws_size,
                              hipStream_t stream) {
    const int* x = (const int*)d_in[0];
    const int* y = (const int*)d_in[1];
    float* out = (float*)d_out;

    signed char* pA = (signed char*)d_ws;                       // 16 MB
    signed char* pB = pA + (size_t)(16u << 20);                 // 16 MB
    int* rsX = (int*)((char*)d_ws + (size_t)(32u << 20));       // 4096 int
    int* csY = rsX + 4096;                                      // 4096 int

    hipMemsetAsync(rsX, 0, 2 * 4096 * sizeof(int), stream);
    pack_a<<<MDIM * KDIM / 16 / 256, 256, 0, stream>>>(x, pA, rsX);
    pack_b<<<KDIM * NDIM / 16 / 256, 256, 0, stream>>>(y, pB);
    colsum_b<<<128, 256, 0, stream>>>(pB, csY);
    gemm_i8<<<dim3(NDIM / 256, MDIM / 256), 512, 0, stream>>>(pA, pB, rsX, csY, out);
}